// Round 11
// baseline (163.991 us; speedup 1.0000x reference)
//
#include <hip/hip_runtime.h>
#include <stdint.h>

typedef short bf16x8 __attribute__((ext_vector_type(8)));
typedef float f32x4 __attribute__((ext_vector_type(4)));

#if __has_builtin(__builtin_amdgcn_exp2f)
#define EXP2F(x) __builtin_amdgcn_exp2f(x)
#else
#define EXP2F(x) exp2f(x)
#endif

// 0.125 (1/sqrt(64)) * log2(e): folded into Q so QK^T scores come out in
// log2 domain directly (softmax uses native v_exp_f32 = exp2).
#define QSCALE 0.18033688011112042f

__device__ __forceinline__ unsigned short f2bf(float f) {
  unsigned u = __float_as_uint(f);
  u += 0x7fffu + ((u >> 16) & 1u);
  return (unsigned short)(u >> 16);
}

// pack 2 fp32 -> 2 bf16 in one dword (RNE), single VALU op
__device__ __forceinline__ unsigned cvtpk(float lo, float hi) {
  unsigned r;
  asm("v_cvt_pk_bf16_f32 %0, %1, %2" : "=v"(r) : "v"(lo), "v"(hi));
  return r;
}

// gfx950 cross-lane swaps (VALU pipe, not DS):
// pl32: a' = [a_lo|b_lo], b' = [a_hi|b_hi]  (32-lane halves)
// pl16: a' = [a0,b0,a2,b2], b' = [a1,b1,a3,b3] (16-lane groups g0..g3)
// HAZARD (r10 lesson): NEVER call these with a==b in value — the allocator
// may coalesce the two "+v" operands into ONE register and the swap
// degenerates to a rotation. Only safe when operands provably differ
// (the P-transpose path qualifies; max-reduction with a=b=x does NOT).
__device__ __forceinline__ void pl32(unsigned& a, unsigned& b) {
  asm("v_permlane32_swap_b32 %0, %1" : "+v"(a), "+v"(b));
}
__device__ __forceinline__ void pl16(unsigned& a, unsigned& b) {
  asm("v_permlane16_swap_b32 %0, %1" : "+v"(a), "+v"(b));
}

// async global->LDS, 16B per lane; LDS dest = waveBase + lane*16 (call sites
// pass &buf[t*8], t = wid*64+lane -> consistent).
__device__ __forceinline__ void gld16(const ushort* g, ushort* l) {
  __builtin_amdgcn_global_load_lds(
      (__attribute__((address_space(1))) void*)g,
      (__attribute__((address_space(3))) void*)l, 16, 0, 0);
}

// ---------------- prep kernels ----------------
__global__ __launch_bounds__(256) void k_cast_bf16(const float* __restrict__ in,
                                                   ushort* __restrict__ out) {
  int i = (blockIdx.x * 256 + threadIdx.x) * 8;
  float4 a = *(const float4*)(in + i);
  float4 b = *(const float4*)(in + i + 4);
  union { ushort u[8]; uint4 q; } r;
  r.u[0] = f2bf(a.x); r.u[1] = f2bf(a.y); r.u[2] = f2bf(a.z); r.u[3] = f2bf(a.w);
  r.u[4] = f2bf(b.x); r.u[5] = f2bf(b.y); r.u[6] = f2bf(b.z); r.u[7] = f2bf(b.w);
  *(uint4*)(out + i) = r.q;
}

// fp32 [R][C] -> bf16 [C][R]
__global__ __launch_bounds__(256) void k_transpose_cast(const float* __restrict__ in,
                                                        ushort* __restrict__ out,
                                                        int R, int C) {
  __shared__ float tl[32][33];
  int t = threadIdx.x;
  {
    int r = t >> 3, c4 = (t & 7) * 4;
    float4 v = *(const float4*)(in + (size_t)(blockIdx.y * 32 + r) * C + blockIdx.x * 32 + c4);
    tl[r][c4] = v.x; tl[r][c4 + 1] = v.y; tl[r][c4 + 2] = v.z; tl[r][c4 + 3] = v.w;
  }
  __syncthreads();
  {
    int c = t >> 3, r4 = (t & 7) * 4;
    union { ushort u[4]; uint2 q; } o;
    o.u[0] = f2bf(tl[r4][c]);     o.u[1] = f2bf(tl[r4 + 1][c]);
    o.u[2] = f2bf(tl[r4 + 2][c]); o.u[3] = f2bf(tl[r4 + 3][c]);
    *(uint2*)(out + (size_t)(blockIdx.x * 32 + c) * R + blockIdx.y * 32 + r4) = o.q;
  }
}

// V [bh][2048][64] -> Vt [bh][64][2048]
__global__ __launch_bounds__(256) void k_vtrans(const ushort* __restrict__ V,
                                                ushort* __restrict__ Vt) {
  __shared__ ushort tl[64 * 72];
  int t = threadIdx.x;
  const ushort* inp = V + (size_t)blockIdx.y * 131072 + blockIdx.x * 4096;
#pragma unroll
  for (int p = 0; p < 2; ++p) {
    int r = (t >> 3) + p * 32, c8 = (t & 7) * 8;
    *(uint4*)&tl[r * 72 + c8] = *(const uint4*)&inp[r * 64 + c8];
  }
  __syncthreads();
  ushort* outp = Vt + (size_t)blockIdx.y * 131072 + blockIdx.x * 64;
#pragma unroll
  for (int p = 0; p < 2; ++p) {
    int d = (t >> 3) + p * 32, s8 = (t & 7) * 8;
    union { ushort u[8]; uint4 q; } o;
#pragma unroll
    for (int j = 0; j < 8; ++j) o.u[j] = tl[(s8 + j) * 72 + d];
    *(uint4*)&outp[d * 2048 + s8] = o.q;
  }
}

// ---------------- GEMM: A[M][1024] bf16 x Bt[N][1024] bf16 ----------------
// m97-verified pattern: LINEAR LDS (no swizzle) + global_load_lds width 16.
// 128x128 tile, BK=32, 4 waves (2x2), each wave 64x64 (4x4 of 16x16 frags).
// MODE 0 epilogue scales the Q third by QSCALE (log2-domain softmax).
template <int MODE>
__global__ __launch_bounds__(256, 2) void k_gemm(
    const ushort* __restrict__ A, const ushort* __restrict__ Bt,
    const float* __restrict__ bias, ushort* __restrict__ Q,
    ushort* __restrict__ Ko, ushort* __restrict__ V, float* __restrict__ Out) {
  __shared__ ushort As[128 * 32];
  __shared__ ushort Bs[128 * 32];
  const int t = threadIdx.x;
  const int lane = t & 63, wid = t >> 6;
  const int wr = wid >> 1, wc = wid & 1;
  const int rt = blockIdx.y, ct = blockIdx.x;

  const int srow = t >> 2, sslot = t & 3;
  const ushort* ga = A + (size_t)(rt * 128 + srow) * 1024 + sslot * 8;
  const ushort* gb = Bt + (size_t)(ct * 128 + srow) * 1024 + sslot * 8;
  ushort* lA = &As[t * 8];
  ushort* lB = &Bs[t * 8];

  f32x4 acc[4][4];
#pragma unroll
  for (int m = 0; m < 4; ++m)
#pragma unroll
    for (int n = 0; n < 4; ++n) acc[m][n] = (f32x4){0.f, 0.f, 0.f, 0.f};

  int aidx[4], bidx[4];
#pragma unroll
  for (int m = 0; m < 4; ++m) {
    int ra = wr * 64 + m * 16 + (lane & 15);
    aidx[m] = ra * 32 + ((lane >> 4) << 3);
    int rb = wc * 64 + m * 16 + (lane & 15);
    bidx[m] = rb * 32 + ((lane >> 4) << 3);
  }

  gld16(ga, lA); gld16(ga + 65536, lA + 2048);
  gld16(gb, lB); gld16(gb + 65536, lB + 2048);

  for (int kt = 0; kt < 32; ++kt) {
    __syncthreads();
    bf16x8 af[4], bfv[4];
#pragma unroll
    for (int m = 0; m < 4; ++m) af[m] = *(const bf16x8*)&As[aidx[m]];
#pragma unroll
    for (int n = 0; n < 4; ++n) bfv[n] = *(const bf16x8*)&Bs[bidx[n]];
    __syncthreads();
    if (kt < 31) {
      const ushort* ga2 = ga + (kt + 1) * 32;
      const ushort* gb2 = gb + (kt + 1) * 32;
      gld16(ga2, lA); gld16(ga2 + 65536, lA + 2048);
      gld16(gb2, lB); gld16(gb2 + 65536, lB + 2048);
    }
#pragma unroll
    for (int m = 0; m < 4; ++m)
#pragma unroll
      for (int n = 0; n < 4; ++n)
        acc[m][n] = __builtin_amdgcn_mfma_f32_16x16x32_bf16(af[m], bfv[n], acc[m][n], 0, 0, 0);
  }

  const int colb = ct * 128 + wc * 64;
  const int rowb = rt * 128 + wr * 64;
  if constexpr (MODE == 0) {
#pragma unroll
    for (int n = 0; n < 4; ++n) {
      int col = colb + n * 16 + (lane & 15);
      float bv = bias[col];
      int three = col >> 10, hx = (col >> 6) & 15, d = col & 63;
      float sc = (three == 0) ? QSCALE : 1.0f;
      ushort* dst = (three == 0) ? Q : (three == 1) ? Ko : V;
#pragma unroll
      for (int m = 0; m < 4; ++m) {
        int r0 = rowb + m * 16 + ((lane >> 4) << 2);
#pragma unroll
        for (int r = 0; r < 4; ++r) {
          int row = r0 + r;
          int b = row >> 11, s = row & 2047;
          dst[(size_t)((b * 16 + hx) * 2048 + s) * 64 + d] = f2bf((acc[m][n][r] + bv) * sc);
        }
      }
    }
  } else {
#pragma unroll
    for (int n = 0; n < 4; ++n) {
      int col = colb + n * 16 + (lane & 15);
      float bv = bias[col];
#pragma unroll
      for (int m = 0; m < 4; ++m) {
        int r0 = rowb + m * 16 + ((lane >> 4) << 2);
#pragma unroll
        for (int r = 0; r < 4; ++r)
          Out[(size_t)(r0 + r) * 1024 + col] = acc[m][n][r] + bv;
      }
    }
  }
}

// ---------------- flash attention v4b: KVBLK=128, shfl max-reduce ----------
// r10 post-mortem: gmax4 (permlane swap with a==b) hit the inline-asm
// register-coalescing hazard -> per-g-lane softmax state diverged ->
// absmax 0.08. v4b reverts the max-reduce to the r9-verified shfl_xor pair;
// KVBLK=128 structure kept: 16 tiles, 16 barriers, 64 MFMA/tile.
// LDS: K dbuf [2][128][72] + V dbuf [2][64][136] = 71.7 KB/block; x2
// blocks/CU = 143 KB <= 160 -> 2 blocks/CU (grid-capped occupancy).
// P->A-frag via permlane (operands always differ -> safe); defer-max
// THR=12; log2-domain softmax.
__global__ __launch_bounds__(256, 2) void k_attn(const ushort* __restrict__ Qb,
                                                 const ushort* __restrict__ Kb,
                                                 const ushort* __restrict__ Vtb,
                                                 ushort* __restrict__ AO) {
  __shared__ ushort Ks[2][128 * 72];
  __shared__ ushort Vs[2][64 * 136];
  const int t = threadIdx.x, lane = t & 63, wid = t >> 6;  // wid 0..3
  const int c = lane & 15, g = lane >> 4;
  const int bh = blockIdx.y, qt = blockIdx.x;
  const ushort* Qh = Qb + (size_t)bh * 131072;
  const ushort* Kh = Kb + (size_t)bh * 131072;
  const ushort* Vh = Vtb + (size_t)bh * 131072;

  bf16x8 qf[2][2];
#pragma unroll
  for (int cb = 0; cb < 2; ++cb)
#pragma unroll
    for (int kk = 0; kk < 2; ++kk) {
      int row = qt * 128 + wid * 32 + cb * 16 + c;
      qf[cb][kk] = *(const bf16x8*)&Qh[row * 64 + kk * 32 + g * 8];
    }

  f32x4 oacc[2][4];
#pragma unroll
  for (int cb = 0; cb < 2; ++cb)
#pragma unroll
    for (int n = 0; n < 4; ++n) oacc[cb][n] = (f32x4){0.f, 0.f, 0.f, 0.f};
  float mrow[2] = {-1e30f, -1e30f}, lpart[2] = {0.f, 0.f};  // q = wid*32+cb*16+c

  // staging: K tile 128x64 (row = t>>1, 32-col half = (t&1)*32);
  //          V tile 64x128 (d = t>>2, 32-col quarter = (t&3)*32). 64B each.
  const int skrow = t >> 1, skcol = (t & 1) * 32;
  const int svrow = t >> 2, svcol = (t & 3) * 32;

  // frag bases (compile-time offsets added in the unrolled loops)
  const int kfb = c * 72 + g * 8;   // + n*16*72 + kk*4*8
  const int vfb = c * 136 + g * 8;  // + nd*16*136 + kk*4*8

  // prologue: tile 0 -> LDS buf0; tile 1 -> regs
  uint4 kr[4], vr[4];
#pragma unroll
  for (int u = 0; u < 4; ++u) {
    kr[u] = *(const uint4*)&Kh[(size_t)skrow * 64 + skcol + u * 8];
    vr[u] = *(const uint4*)&Vh[(size_t)svrow * 2048 + svcol + u * 8];
  }
#pragma unroll
  for (int u = 0; u < 4; ++u) {
    *(uint4*)&Ks[0][skrow * 72 + skcol + u * 8] = kr[u];
    *(uint4*)&Vs[0][svrow * 136 + svcol + u * 8] = vr[u];
  }
#pragma unroll
  for (int u = 0; u < 4; ++u) {
    kr[u] = *(const uint4*)&Kh[(size_t)(128 + skrow) * 64 + skcol + u * 8];
    vr[u] = *(const uint4*)&Vh[(size_t)svrow * 2048 + 128 + svcol + u * 8];
  }
  __syncthreads();

  int cur = 0;
  for (int kt = 0; kt < 16; ++kt) {
    const ushort* Kc = &Ks[cur][0];
    const ushort* Vc = &Vs[cur][0];
    // QK^T swapped: sacc[cb][n] lane(c,g) reg r = S[q=..+c][k=n*16+g*4+r]
    f32x4 sacc[2][8];
#pragma unroll
    for (int cb = 0; cb < 2; ++cb)
#pragma unroll
      for (int n = 0; n < 8; ++n) sacc[cb][n] = (f32x4){0.f, 0.f, 0.f, 0.f};
    __builtin_amdgcn_s_setprio(1);
#pragma unroll
    for (int kk = 0; kk < 2; ++kk)
#pragma unroll
      for (int n = 0; n < 8; ++n) {
        bf16x8 kf = *(const bf16x8*)&Kc[kfb + n * 1152 + kk * 32];
        sacc[0][n] = __builtin_amdgcn_mfma_f32_16x16x32_bf16(kf, qf[0][kk], sacc[0][n], 0, 0, 0);
        sacc[1][n] = __builtin_amdgcn_mfma_f32_16x16x32_bf16(kf, qf[1][kk], sacc[1][n], 0, 0, 0);
      }
    __builtin_amdgcn_s_setprio(0);
    // softmax per cb: in-lane tree + 2 shfl_xor cross-g reduce (r9-verified)
    uint2 W[2][8];
#pragma unroll
    for (int cb = 0; cb < 2; ++cb) {
      f32x4 m4 = sacc[cb][0];
#pragma unroll
      for (int n = 1; n < 8; ++n) {
        m4[0] = fmaxf(m4[0], sacc[cb][n][0]);
        m4[1] = fmaxf(m4[1], sacc[cb][n][1]);
        m4[2] = fmaxf(m4[2], sacc[cb][n][2]);
        m4[3] = fmaxf(m4[3], sacc[cb][n][3]);
      }
      float mx = fmaxf(fmaxf(m4[0], m4[1]), fmaxf(m4[2], m4[3]));
      mx = fmaxf(mx, __shfl_xor(mx, 16));
      mx = fmaxf(mx, __shfl_xor(mx, 32));
      if (!__all(mx <= mrow[cb] + 12.0f)) {
        float mo = mrow[cb];
        float mn = fmaxf(mo, mx);
        float corr = EXP2F(mo - mn);  // corr for q-row c
        mrow[cb] = mn;
        lpart[cb] *= corr;
#pragma unroll
        for (int r = 0; r < 4; ++r) {  // oacc rows are q = g*4+r
          float cr = __shfl(corr, (g << 2) + r);
          oacc[cb][0][r] *= cr; oacc[cb][1][r] *= cr;
          oacc[cb][2][r] *= cr; oacc[cb][3][r] *= cr;
        }
      }
      const float mu = mrow[cb];
      float ps = lpart[cb];
#pragma unroll
      for (int n = 0; n < 8; ++n) {
        float p0 = EXP2F(sacc[cb][n][0] - mu);
        float p1 = EXP2F(sacc[cb][n][1] - mu);
        float p2 = EXP2F(sacc[cb][n][2] - mu);
        float p3 = EXP2F(sacc[cb][n][3] - mu);
        ps += (p0 + p1) + (p2 + p3);
        W[cb][n].x = cvtpk(p0, p1);
        W[cb][n].y = cvtpk(p2, p3);
      }
      lpart[cb] = ps;
    }
    // PV: A-frags via permlane swaps (distinct operands -> safe); kk = 0..3
    __builtin_amdgcn_s_setprio(1);
#pragma unroll
    for (int kk = 0; kk < 4; ++kk) {
      bf16x8 paf[2];
#pragma unroll
      for (int cb = 0; cb < 2; ++cb) {
        unsigned a0 = W[cb][2 * kk].x, b0 = W[cb][2 * kk + 1].x;
        pl32(a0, b0); pl16(a0, b0);  // a0 = D0 (k+0,1), b0 = D2 (k+4,5)
        unsigned a1 = W[cb][2 * kk].y, b1 = W[cb][2 * kk + 1].y;
        pl32(a1, b1); pl16(a1, b1);  // a1 = D1 (k+2,3), b1 = D3 (k+6,7)
        union { unsigned u[4]; bf16x8 v; } fr;
        fr.u[0] = a0; fr.u[1] = a1; fr.u[2] = b0; fr.u[3] = b1;
        paf[cb] = fr.v;
      }
#pragma unroll
      for (int nd = 0; nd < 4; ++nd) {
        bf16x8 vf = *(const bf16x8*)&Vc[vfb + nd * 2176 + kk * 32];
        oacc[0][nd] = __builtin_amdgcn_mfma_f32_16x16x32_bf16(paf[0], vf, oacc[0][nd], 0, 0, 0);
        oacc[1][nd] = __builtin_amdgcn_mfma_f32_16x16x32_bf16(paf[1], vf, oacc[1][nd], 0, 0, 0);
      }
    }
    __builtin_amdgcn_s_setprio(0);
    // stage prefetched tile kt+1 into the other buffer, then prefetch kt+2
    if (kt < 15) {
      ushort* kd = &Ks[cur ^ 1][skrow * 72 + skcol];
      ushort* vd = &Vs[cur ^ 1][svrow * 136 + svcol];
#pragma unroll
      for (int u = 0; u < 4; ++u) {
        *(uint4*)(kd + u * 8) = kr[u];
        *(uint4*)(vd + u * 8) = vr[u];
      }
      if (kt < 14) {
#pragma unroll
        for (int u = 0; u < 4; ++u) {
          kr[u] = *(const uint4*)&Kh[(size_t)((kt + 2) * 128 + skrow) * 64 + skcol + u * 8];
          vr[u] = *(const uint4*)&Vh[(size_t)svrow * 2048 + (kt + 2) * 128 + svcol + u * 8];
        }
      }
    }
    __syncthreads();
    cur ^= 1;
  }

  const int b = bh >> 4, h = bh & 15;
#pragma unroll
  for (int cb = 0; cb < 2; ++cb) {
    float lp = lpart[cb];
    lp += __shfl_xor(lp, 16);
    lp += __shfl_xor(lp, 32);
    float inv = 1.0f / lp;  // for q-row c of this cb
    float invr[4];
#pragma unroll
    for (int r = 0; r < 4; ++r) invr[r] = __shfl(inv, (g << 2) + r);
#pragma unroll
    for (int nd = 0; nd < 4; ++nd) {
      int d = nd * 16 + c;
#pragma unroll
      for (int r = 0; r < 4; ++r) {
        int s = qt * 128 + wid * 32 + cb * 16 + (g << 2) + r;
        AO[(size_t)((b * 2048 + s) * 16 + h) * 64 + d] = f2bf(oacc[cb][nd][r] * invr[r]);
      }
    }
  }
}

extern "C" void kernel_launch(void* const* d_in, const int* in_sizes, int n_in,
                              void* d_out, int out_size, void* d_ws, size_t ws_size,
                              hipStream_t stream) {
  const float* x = (const float*)d_in[0];
  const float* w_qkv = (const float*)d_in[1];
  const float* b_qkv = (const float*)d_in[2];
  const float* w_out = (const float*)d_in[3];
  const float* b_out = (const float*)d_in[4];
  float* out = (float*)d_out;

  char* p = (char*)d_ws;
  ushort* xb = (ushort*)p;    p += (size_t)4096 * 1024 * 2;   // reused as AO later
  ushort* wqkvT = (ushort*)p; p += (size_t)3072 * 1024 * 2;
  ushort* woutT = (ushort*)p; p += (size_t)1024 * 1024 * 2;
  ushort* Qb = (ushort*)p;    p += (size_t)32 * 2048 * 64 * 2;
  ushort* Kb = (ushort*)p;    p += (size_t)32 * 2048 * 64 * 2;
  ushort* Vb = (ushort*)p;    p += (size_t)32 * 2048 * 64 * 2;
  ushort* Vtb = (ushort*)p;   p += (size_t)32 * 2048 * 64 * 2;
  ushort* AO = xb;  // xb dead after QKV GEMM; reuse (stream-ordered, safe)

  k_cast_bf16<<<2048, 256, 0, stream>>>(x, xb);
  k_transpose_cast<<<dim3(96, 32), 256, 0, stream>>>(w_qkv, wqkvT, 1024, 3072);
  k_transpose_cast<<<dim3(32, 32), 256, 0, stream>>>(w_out, woutT, 1024, 1024);
  k_gemm<0><<<dim3(24, 32), 256, 0, stream>>>(xb, wqkvT, b_qkv, Qb, Kb, Vb, nullptr);
  k_vtrans<<<dim3(32, 32), 256, 0, stream>>>(Vb, Vtb);
  k_attn<<<dim3(16, 32), 256, 0, stream>>>(Qb, Kb, Vtb, AO);
  k_gemm<1><<<dim3(8, 32), 256, 0, stream>>>(AO, woutT, b_out, nullptr, nullptr, nullptr, out);
}